// Round 14
// baseline (891.606 us; speedup 1.0000x reference)
//
#include <hip/hip_runtime.h>
#include <hip/hip_bf16.h>
#include <stdint.h>

#define SEQ    2048
#define HIDDEN 4096
#define INTER  11008

typedef short bf16x8 __attribute__((ext_vector_type(8)));
typedef float f32x4  __attribute__((ext_vector_type(4)));
typedef unsigned short u16x8 __attribute__((ext_vector_type(8)));

#define BAR()  asm volatile("s_barrier" ::: "memory")
#define W4()   asm volatile("s_waitcnt vmcnt(4)" ::: "memory")
#define W2()   asm volatile("s_waitcnt vmcnt(2)" ::: "memory")
#define W0()   asm volatile("s_waitcnt vmcnt(0)" ::: "memory")

__device__ __forceinline__ unsigned short f2bf(float f) {
    union { __hip_bfloat16 h; unsigned short u; } v;
    v.h = __float2bfloat16(f);
    return v.u;
}

__device__ __forceinline__ void gload_lds16(const void* g, void* lds) {
    __builtin_amdgcn_global_load_lds(
        (const __attribute__((address_space(1))) uint32_t*)g,
        (__attribute__((address_space(3))) uint32_t*)lds,
        16, 0, 0);
}

// ---------------------------------------------------------------------------
// Dequant work unit: one 512-thread block handles 4096 codes (bf16 out).
// ---------------------------------------------------------------------------
__device__ __forceinline__ void deq_block(
    const int* __restrict__ qw, const int* __restrict__ qz,
    const float* __restrict__ sc, unsigned short* __restrict__ w,
    int db, int t)
{
    size_t i = (size_t)db * 4096 + (size_t)t * 8;
    int gi = (int)(i >> 7);
    int   z = qz[gi];
    float s = sc[gi];
    float zs = -(float)z * s;
    int4 q0 = *(const int4*)(qw + i);
    int4 q1 = *(const int4*)(qw + i + 4);
    u16x8 o;
    o[0] = f2bf(fmaf((float)q0.x, s, zs));
    o[1] = f2bf(fmaf((float)q0.y, s, zs));
    o[2] = f2bf(fmaf((float)q0.z, s, zs));
    o[3] = f2bf(fmaf((float)q0.w, s, zs));
    o[4] = f2bf(fmaf((float)q1.x, s, zs));
    o[5] = f2bf(fmaf((float)q1.y, s, zs));
    o[6] = f2bf(fmaf((float)q1.z, s, zs));
    o[7] = f2bf(fmaf((float)q1.w, s, zs));
    *(u16x8*)(w + i) = o;
}

// ---------------------------------------------------------------------------
// Prep kernel: cvt x (blocks 0..2047) + dequant gate (2048..13055)
// + dequant up (13056..24063). All independent.
// ---------------------------------------------------------------------------
__global__ __launch_bounds__(512) void k_prep(
    const float* __restrict__ x, unsigned short* __restrict__ xb,
    const int* __restrict__ gqw, const int* __restrict__ gqz,
    const float* __restrict__ gsc, unsigned short* __restrict__ wgb,
    const int* __restrict__ uqw, const int* __restrict__ uqz,
    const float* __restrict__ usc, unsigned short* __restrict__ wub)
{
    const int bid = blockIdx.x;
    const int t   = threadIdx.x;
    if (bid < 2048) {
        size_t i = ((size_t)bid * 512 + t) * 8;
        float4 v0 = *(const float4*)(x + i);
        float4 v1 = *(const float4*)(x + i + 4);
        u16x8 o;
        o[0] = f2bf(v0.x); o[1] = f2bf(v0.y); o[2] = f2bf(v0.z); o[3] = f2bf(v0.w);
        o[4] = f2bf(v1.x); o[5] = f2bf(v1.y); o[6] = f2bf(v1.z); o[7] = f2bf(v1.w);
        *(u16x8*)(xb + i) = o;
    } else if (bid < 13056) {
        deq_block(gqw, gqz, gsc, wgb, bid - 2048, t);
    } else {
        deq_block(uqw, uqz, usc, wub, bid - 13056, t);
    }
}

// Standalone down-dequant (fallback path when ws is too small to de-alias).
__global__ __launch_bounds__(512) void k_deq_fb(
    const int* __restrict__ qw, const int* __restrict__ qz,
    const float* __restrict__ sc, unsigned short* __restrict__ w)
{
    deq_block(qw, qz, sc, w, blockIdx.x, threadIdx.x);
}

// ---------------------------------------------------------------------------
// Fused gate+up GEMM + SwiGLU -> h (bf16), m201-cadence 8-phase port.
// 512 thr (8 waves: 4M x 2N). Tile 256(M) x 128(N), BK=64, dbuf-2 LDS 128 KB
// (1 block/CU by design). Wave tile 64M x 64N for BOTH matrices -> frag
// traffic 24 KB/wave/K-tile for 64 MFMA (AI cap: MFMA 1240cy / LDS 2000cy
// = 62% MfmaUtil, m201's number). 4 phases/K-tile, each:
//   {issue one 2-load prefetch group | counted vmcnt | BAR | ds_read subtile
//    | setprio 16 MFMA | BAR}.  vmcnt(4) at ph0/ph1 only; never 0 in loop.
// Grid 688 = 8 Mtiles x 86 Ntiles (XCD swz, M-siblings adjacent)
// + 11008 co-scheduled down-dequant blocks (blockIdx >= 688).
// ---------------------------------------------------------------------------
__global__ __launch_bounds__(512) void k_gate_up(
    const unsigned short* __restrict__ xb,   // [SEQ][HIDDEN] bf16
    const unsigned short* __restrict__ wg,   // [INTER][HIDDEN] bf16
    const unsigned short* __restrict__ wu,   // [INTER][HIDDEN] bf16
    const float* __restrict__ gbias, const float* __restrict__ ubias,
    unsigned short* __restrict__ h,          // [SEQ][INTER] bf16
    const int* __restrict__ dqw, const int* __restrict__ dqz,
    const float* __restrict__ dsc, unsigned short* __restrict__ wdb)
{
    __shared__ __align__(16) unsigned short A_[2][256 * 64];  // 64 KB
    __shared__ __align__(16) unsigned short Bg_[2][128 * 64]; // 32 KB
    __shared__ __align__(16) unsigned short Bu_[2][128 * 64]; // 32 KB

    if (blockIdx.x >= 688) {         // co-scheduled down-dequant block
        deq_block(dqw, dqz, dsc, wdb, blockIdx.x - 688, threadIdx.x);
        return;
    }

    const int orig = blockIdx.x;                  // 688 = 8 * 86
    const int swz  = (orig & 7) * 86 + (orig >> 3);
    const int mt   = swz & 7;                     // M-siblings adjacent
    const int nt   = swz >> 3;                    // 0..85
    const int m0   = mt * 256;
    const int n0   = nt * 128;

    const int t    = threadIdx.x;
    const int lane = t & 63;
    const int wave = t >> 6;
    const int wm = (wave >> 1) * 64;              // 0,64,128,192
    const int wn = (wave & 1) * 64;               // 0,64

    f32x4 accG[4][4], accU[4][4];
#pragma unroll
    for (int mi = 0; mi < 4; ++mi)
#pragma unroll
        for (int ni = 0; ni < 4; ++ni) {
            accG[mi][ni] = (f32x4){0.f, 0.f, 0.f, 0.f};
            accU[mi][ni] = (f32x4){0.f, 0.f, 0.f, 0.f};
        }

    // ---- staging groups: 2 loads/thread each; per-thread FIFO order is
    //      [A0, A1, Bg, Bu] within a K-tile (issued at ph0..ph3) ----
    auto stA0 = [&](int buf, int kt) {
        const int k0 = kt * 64;
#pragma unroll
        for (int cc = 0; cc < 2; ++cc) {
            int idx  = t + 512 * cc;              // 0..1023, rows 0..127
            int row  = idx >> 3;
            int scol = ((idx & 7) * 16) ^ ((row & 7) << 4);
            gload_lds16((const char*)(xb + (size_t)(m0 + row) * HIDDEN + k0) + scol,
                        (char*)A_[buf] + idx * 16);
        }
    };
    auto stA1 = [&](int buf, int kt) {
        const int k0 = kt * 64;
#pragma unroll
        for (int cc = 0; cc < 2; ++cc) {
            int idx  = t + 512 * cc;              // rows 128..255
            int row  = idx >> 3;
            int scol = ((idx & 7) * 16) ^ ((row & 7) << 4);
            gload_lds16((const char*)(xb + (size_t)(m0 + 128 + row) * HIDDEN + k0) + scol,
                        (char*)A_[buf] + 16384 + idx * 16);
        }
    };
    auto stG = [&](int buf, int kt) {
        const int k0 = kt * 64;
#pragma unroll
        for (int cc = 0; cc < 2; ++cc) {
            int idx  = t + 512 * cc;
            int row  = idx >> 3;
            int scol = ((idx & 7) * 16) ^ ((row & 7) << 4);
            gload_lds16((const char*)(wg + (size_t)(n0 + row) * HIDDEN + k0) + scol,
                        (char*)Bg_[buf] + idx * 16);
        }
    };
    auto stU = [&](int buf, int kt) {
        const int k0 = kt * 64;
#pragma unroll
        for (int cc = 0; cc < 2; ++cc) {
            int idx  = t + 512 * cc;
            int row  = idx >> 3;
            int scol = ((idx & 7) * 16) ^ ((row & 7) << 4);
            gload_lds16((const char*)(wu + (size_t)(n0 + row) * HIDDEN + k0) + scol,
                        (char*)Bu_[buf] + idx * 16);
        }
    };

    auto rdA = [&](int buf, int kk, bf16x8* af) {
#pragma unroll
        for (int mi = 0; mi < 4; ++mi) {
            int row  = wm + mi * 16 + (lane & 15);   // 0..255
            int colb = kk * 64 + ((lane >> 4) * 16);
            af[mi] = *(const bf16x8*)((const char*)A_[buf] + row * 128 +
                                      (colb ^ ((row & 7) << 4)));
        }
    };
    auto rdB = [&](const unsigned short* Bt, int kk, bf16x8* bb) {
#pragma unroll
        for (int ni = 0; ni < 4; ++ni) {
            int row  = wn + ni * 16 + (lane & 15);   // 0..127
            int colb = kk * 64 + ((lane >> 4) * 16);
            bb[ni] = *(const bf16x8*)((const char*)Bt + row * 128 +
                                      (colb ^ ((row & 7) << 4)));
        }
    };
    auto mmG = [&](const bf16x8* af, const bf16x8* bb) {
        __builtin_amdgcn_s_setprio(1);
#pragma unroll
        for (int mi = 0; mi < 4; ++mi)
#pragma unroll
            for (int ni = 0; ni < 4; ++ni)
                accG[mi][ni] = __builtin_amdgcn_mfma_f32_16x16x32_bf16(
                    af[mi], bb[ni], accG[mi][ni], 0, 0, 0);
        __builtin_amdgcn_s_setprio(0);
    };
    auto mmU = [&](const bf16x8* af, const bf16x8* bb) {
        __builtin_amdgcn_s_setprio(1);
#pragma unroll
        for (int mi = 0; mi < 4; ++mi)
#pragma unroll
            for (int ni = 0; ni < 4; ++ni)
                accU[mi][ni] = __builtin_amdgcn_mfma_f32_16x16x32_bf16(
                    af[mi], bb[ni], accU[mi][ni], 0, 0, 0);
        __builtin_amdgcn_s_setprio(0);
    };

    // prologue: stage K-tile 0 (8 loads/thread, FIFO [A0,A1,Bg,Bu])
    stA0(0, 0); stA1(0, 0); stG(0, 0); stU(0, 0);

    for (int kt = 0; kt < 63; ++kt) {            // NT = 64, peel last
        const int b = kt & 1;
        bf16x8 af[4], bb[4];
        // ph0: issue A0(kt+1) | need A0,A1,Bg(kt): newer = Bu(kt)+A0(kt+1)=4
        stA0(b ^ 1, kt + 1); W4(); BAR();
        rdA(b, 0, af); rdB(Bg_[b], 0, bb); mmG(af, bb); BAR();
        // ph1: issue A1(kt+1) | need Bu(kt): newer = A0,A1(kt+1) = 4
        stA1(b ^ 1, kt + 1); W4(); BAR();
        rdB(Bu_[b], 0, bb); mmU(af, bb); BAR();
        // ph2: issue Bg(kt+1) | all tile-kt data resident, no vmcnt
        stG(b ^ 1, kt + 1); BAR();
        rdA(b, 1, af); rdB(Bg_[b], 1, bb); mmG(af, bb); BAR();
        // ph3: issue Bu(kt+1)
        stU(b ^ 1, kt + 1); BAR();
        rdB(Bu_[b], 1, bb); mmU(af, bb); BAR();
    }
    {   // peeled kt = 63 (buf 1): nothing to issue
        bf16x8 af[4], bb[4];
        W2(); BAR();                              // A0,A1,Bg done (Bu may fly)
        rdA(1, 0, af); rdB(Bg_[1], 0, bb); mmG(af, bb); BAR();
        W0(); BAR();                              // Bu done
        rdB(Bu_[1], 0, bb); mmU(af, bb); BAR();
        rdA(1, 1, af); rdB(Bg_[1], 1, bb); mmG(af, bb); BAR();
        rdB(Bu_[1], 1, bb); mmU(af, bb);
    }

    // ---- epilogue: SwiGLU ----
#pragma unroll
    for (int ni = 0; ni < 4; ++ni) {
        int col = n0 + wn + ni * 16 + (lane & 15);
        float gb = gbias[col], ub = ubias[col];
#pragma unroll
        for (int mi = 0; mi < 4; ++mi) {
#pragma unroll
            for (int j = 0; j < 4; ++j) {
                int row = m0 + wm + mi * 16 + ((lane >> 4) * 4) + j;
                float g = accG[mi][ni][j] + gb;
                float u = accU[mi][ni][j] + ub;
                float sig = 1.f / (1.f + __expf(-g));
                h[(size_t)row * INTER + col] = f2bf(g * sig * u);
            }
        }
    }
}

// ---------------------------------------------------------------------------
// Down GEMM: y = h @ Wd^T + bias (fp32 out). [R9-proven, unchanged]
// 512 thr, tile 128x128, BK=64. Grid 512 = 8 * 64, XCD swizzle.
// ---------------------------------------------------------------------------
__global__ __launch_bounds__(512) void k_down(
    const unsigned short* __restrict__ h,    // [SEQ][INTER] bf16
    const unsigned short* __restrict__ wd,   // [HIDDEN][INTER] bf16
    const float* __restrict__ dbias,
    float* __restrict__ y)                   // [SEQ][HIDDEN] fp32
{
    __shared__ __align__(16) unsigned short At[128 * 64]; // 16 KB
    __shared__ __align__(16) unsigned short Bd[128 * 64]; // 16 KB

    const int orig = blockIdx.x;                  // 512 = 8 * 64
    const int swz  = (orig & 7) * 64 + (orig >> 3);
    const int mt   = swz & 15;
    const int nt   = swz >> 4;
    const int m0   = mt * 128;
    const int n0   = nt * 128;

    const int t    = threadIdx.x;
    const int lane = t & 63;
    const int wave = t >> 6;
    const int wm = (wave >> 2) * 64;
    const int wn = (wave & 3) * 32;

    f32x4 acc[4][2];
#pragma unroll
    for (int mi = 0; mi < 4; ++mi)
#pragma unroll
        for (int ni = 0; ni < 2; ++ni)
            acc[mi][ni] = (f32x4){0.f, 0.f, 0.f, 0.f};

    for (int kt = 0; kt < INTER / 64; ++kt) {
        const int k0 = kt * 64;

#pragma unroll
        for (int cc = 0; cc < 2; ++cc) {
            int idx  = t + 512 * cc;
            int row  = idx >> 3;
            int scol = ((idx & 7) * 16) ^ ((row & 7) << 4);
            gload_lds16((const char*)(h + (size_t)(m0 + row) * INTER + k0) + scol,
                        (char*)At + idx * 16);
            gload_lds16((const char*)(wd + (size_t)(n0 + row) * INTER + k0) + scol,
                        (char*)Bd + idx * 16);
        }

        __syncthreads();

#pragma unroll
        for (int kk = 0; kk < 2; ++kk) {
            bf16x8 af[4], bd[2];
#pragma unroll
            for (int mi = 0; mi < 4; ++mi) {
                int row  = wm + mi * 16 + (lane & 15);
                int colb = kk * 64 + ((lane >> 4) * 16);
                af[mi] = *(const bf16x8*)((const char*)At + row * 128 +
                                          (colb ^ ((row & 7) << 4)));
            }
#pragma unroll
            for (int ni = 0; ni < 2; ++ni) {
                int row  = wn + ni * 16 + (lane & 15);
                int colb = kk * 64 + ((lane >> 4) * 16);
                bd[ni] = *(const bf16x8*)((const char*)Bd + row * 128 +
                                          (colb ^ ((row & 7) << 4)));
            }
            __builtin_amdgcn_s_setprio(1);
#pragma unroll
            for (int mi = 0; mi < 4; ++mi)
#pragma unroll
                for (int ni = 0; ni < 2; ++ni)
                    acc[mi][ni] = __builtin_amdgcn_mfma_f32_16x16x32_bf16(
                        af[mi], bd[ni], acc[mi][ni], 0, 0, 0);
            __builtin_amdgcn_s_setprio(0);
        }

        __syncthreads();
    }

#pragma unroll
    for (int ni = 0; ni < 2; ++ni) {
        int col = n0 + wn + ni * 16 + (lane & 15);
        float db = dbias[col];
#pragma unroll
        for (int mi = 0; mi < 4; ++mi) {
#pragma unroll
            for (int j = 0; j < 4; ++j) {
                int row = m0 + wm + mi * 16 + ((lane >> 4) * 4) + j;
                y[(size_t)row * HIDDEN + col] = acc[mi][ni][j] + db;
            }
        }
    }
}

// ---------------------------------------------------------------------------
extern "C" void kernel_launch(void* const* d_in, const int* in_sizes, int n_in,
                              void* d_out, int out_size, void* d_ws, size_t ws_size,
                              hipStream_t stream) {
    const float* x    = (const float*)d_in[0];
    const int*   gqw  = (const int*)d_in[1];
    const int*   gqz  = (const int*)d_in[2];
    const float* gsc  = (const float*)d_in[3];
    const float* gbia = (const float*)d_in[4];
    const int*   uqw  = (const int*)d_in[5];
    const int*   uqz  = (const int*)d_in[6];
    const float* usc  = (const float*)d_in[7];
    const float* ubia = (const float*)d_in[8];
    const int*   dqw  = (const int*)d_in[9];
    const int*   dqz  = (const int*)d_in[10];
    const float* dsc  = (const float*)d_in[11];
    const float* dbia = (const float*)d_in[12];
    float* y = (float*)d_out;

    const size_t N_XB = (size_t)SEQ * HIDDEN;      // 8.4M
    const size_t N_H  = (size_t)SEQ * INTER;       // 22.5M
    const size_t N_W  = (size_t)INTER * HIDDEN;    // 45.1M

    unsigned short* xb  = (unsigned short*)d_ws;
    unsigned short* hh  = xb + N_XB;
    unsigned short* wgb = hh + N_H;
    unsigned short* wub = wgb + N_W;

    const size_t need_big = (N_XB + N_H + 3 * N_W) * sizeof(unsigned short);
    const bool   big      = ws_size >= need_big;

    // prep: cvt + dequant gate + dequant up (2048 + 11008 + 11008 blocks)
    k_prep<<<dim3(24064), 512, 0, stream>>>(x, xb, gqw, gqz, gsc, wgb,
                                            uqw, uqz, usc, wub);

    if (big) {
        unsigned short* wdb = wub + N_W;           // de-aliased down weights
        // GEMM (688) + co-scheduled down-dequant (11008) in one grid
        k_gate_up<<<dim3(688 + 11008), 512, 0, stream>>>(
            xb, wgb, wub, gbia, ubia, hh, dqw, dqz, dsc, wdb);
        k_down<<<dim3(512), 512, 0, stream>>>(hh, wdb, dbia, y);
    } else {
        unsigned short* wdb = wgb;                 // alias: serial fallback
        k_gate_up<<<dim3(688), 512, 0, stream>>>(
            xb, wgb, wub, gbia, ubia, hh, dqw, dqz, dsc, wdb);
        k_deq_fb<<<dim3(11008), 512, 0, stream>>>(dqw, dqz, dsc, wdb);
        k_down<<<dim3(512), 512, 0, stream>>>(hh, wdb, dbia, y);
    }
}

// Round 15
// 699.574 us; speedup vs baseline: 1.2745x; 1.2745x over previous
//
#include <hip/hip_runtime.h>
#include <hip/hip_bf16.h>
#include <stdint.h>

#define SEQ    2048
#define HIDDEN 4096
#define INTER  11008

typedef short bf16x8 __attribute__((ext_vector_type(8)));
typedef float f32x4  __attribute__((ext_vector_type(4)));
typedef unsigned short u16x8 __attribute__((ext_vector_type(8)));

__device__ __forceinline__ unsigned short f2bf(float f) {
    union { __hip_bfloat16 h; unsigned short u; } v;
    v.h = __float2bfloat16(f);
    return v.u;
}

__device__ __forceinline__ void gload_lds16(const void* g, void* lds) {
    __builtin_amdgcn_global_load_lds(
        (const __attribute__((address_space(1))) uint32_t*)g,
        (__attribute__((address_space(3))) uint32_t*)lds,
        16, 0, 0);
}

// ---------------------------------------------------------------------------
// Dequant work unit: one 512-thread block handles 4096 codes (bf16 out).
// ---------------------------------------------------------------------------
__device__ __forceinline__ void deq_block(
    const int* __restrict__ qw, const int* __restrict__ qz,
    const float* __restrict__ sc, unsigned short* __restrict__ w,
    int db, int t)
{
    size_t i = (size_t)db * 4096 + (size_t)t * 8;
    int gi = (int)(i >> 7);
    int   z = qz[gi];
    float s = sc[gi];
    float zs = -(float)z * s;
    int4 q0 = *(const int4*)(qw + i);
    int4 q1 = *(const int4*)(qw + i + 4);
    u16x8 o;
    o[0] = f2bf(fmaf((float)q0.x, s, zs));
    o[1] = f2bf(fmaf((float)q0.y, s, zs));
    o[2] = f2bf(fmaf((float)q0.z, s, zs));
    o[3] = f2bf(fmaf((float)q0.w, s, zs));
    o[4] = f2bf(fmaf((float)q1.x, s, zs));
    o[5] = f2bf(fmaf((float)q1.y, s, zs));
    o[6] = f2bf(fmaf((float)q1.z, s, zs));
    o[7] = f2bf(fmaf((float)q1.w, s, zs));
    *(u16x8*)(w + i) = o;
}

// ---------------------------------------------------------------------------
// Prep kernel: cvt x (blocks 0..2047) + dequant gate (2048..13055)
// + dequant up (13056..24063). All independent.
// ---------------------------------------------------------------------------
__global__ __launch_bounds__(512) void k_prep(
    const float* __restrict__ x, unsigned short* __restrict__ xb,
    const int* __restrict__ gqw, const int* __restrict__ gqz,
    const float* __restrict__ gsc, unsigned short* __restrict__ wgb,
    const int* __restrict__ uqw, const int* __restrict__ uqz,
    const float* __restrict__ usc, unsigned short* __restrict__ wub)
{
    const int bid = blockIdx.x;
    const int t   = threadIdx.x;
    if (bid < 2048) {
        size_t i = ((size_t)bid * 512 + t) * 8;
        float4 v0 = *(const float4*)(x + i);
        float4 v1 = *(const float4*)(x + i + 4);
        u16x8 o;
        o[0] = f2bf(v0.x); o[1] = f2bf(v0.y); o[2] = f2bf(v0.z); o[3] = f2bf(v0.w);
        o[4] = f2bf(v1.x); o[5] = f2bf(v1.y); o[6] = f2bf(v1.z); o[7] = f2bf(v1.w);
        *(u16x8*)(xb + i) = o;
    } else if (bid < 13056) {
        deq_block(gqw, gqz, gsc, wgb, bid - 2048, t);
    } else {
        deq_block(uqw, uqz, usc, wub, bid - 13056, t);
    }
}

// Standalone down-dequant (fallback path when ws is too small to de-alias).
__global__ __launch_bounds__(512) void k_deq_fb(
    const int* __restrict__ qw, const int* __restrict__ qz,
    const float* __restrict__ sc, unsigned short* __restrict__ w)
{
    deq_block(qw, qz, sc, w, blockIdx.x, threadIdx.x);
}

// ---------------------------------------------------------------------------
// Fused gate+up GEMM + SwiGLU -> h (bf16)  [R4/R9-proven core + XCD swizzle]
// 512 thr (8 waves: 2M x 4N). Tile 128x128, BK=64, single-buf 48 KB,
// 2 blocks/CU (regs ~64 arch + 64 acc). Grid 1376 GEMM blocks
// (+ optional 11008 down-dequant blocks co-scheduled, blockIdx >= 1376).
// ---------------------------------------------------------------------------
__global__ __launch_bounds__(512) void k_gate_up(
    const unsigned short* __restrict__ xb,   // [SEQ][HIDDEN] bf16
    const unsigned short* __restrict__ wg,   // [INTER][HIDDEN] bf16
    const unsigned short* __restrict__ wu,   // [INTER][HIDDEN] bf16
    const float* __restrict__ gbias, const float* __restrict__ ubias,
    unsigned short* __restrict__ h,          // [SEQ][INTER] bf16
    const int* __restrict__ dqw, const int* __restrict__ dqz,
    const float* __restrict__ dsc, unsigned short* __restrict__ wdb)
{
    __shared__ __align__(16) unsigned short At[128 * 64]; // 16 KB, swizzled
    __shared__ __align__(16) unsigned short Bg[128 * 64]; // 16 KB
    __shared__ __align__(16) unsigned short Bu[128 * 64]; // 16 KB

    if (blockIdx.x >= 1376) {        // co-scheduled down-dequant block
        deq_block(dqw, dqz, dsc, wdb, blockIdx.x - 1376, threadIdx.x);
        return;
    }

    const int orig = blockIdx.x;                  // 1376 = 8 * 172
    const int swz  = (orig & 7) * 172 + (orig >> 3);
    const int mt   = swz & 15;                    // M-siblings adjacent
    const int nt   = swz >> 4;
    const int m0   = mt * 128;
    const int n0   = nt * 128;

    const int t    = threadIdx.x;
    const int lane = t & 63;
    const int wave = t >> 6;
    const int wm = (wave >> 2) * 64;
    const int wn = (wave & 3) * 32;

    f32x4 accG[4][2], accU[4][2];
#pragma unroll
    for (int mi = 0; mi < 4; ++mi)
#pragma unroll
        for (int ni = 0; ni < 2; ++ni) {
            accG[mi][ni] = (f32x4){0.f, 0.f, 0.f, 0.f};
            accU[mi][ni] = (f32x4){0.f, 0.f, 0.f, 0.f};
        }

    for (int kt = 0; kt < HIDDEN / 64; ++kt) {
        const int k0 = kt * 64;

#pragma unroll
        for (int cc = 0; cc < 2; ++cc) {
            int idx  = t + 512 * cc;
            int row  = idx >> 3;
            int scol = ((idx & 7) * 16) ^ ((row & 7) << 4);
            gload_lds16((const char*)(xb + (size_t)(m0 + row) * HIDDEN + k0) + scol,
                        (char*)At + idx * 16);
            gload_lds16((const char*)(wg + (size_t)(n0 + row) * HIDDEN + k0) + scol,
                        (char*)Bg + idx * 16);
            gload_lds16((const char*)(wu + (size_t)(n0 + row) * HIDDEN + k0) + scol,
                        (char*)Bu + idx * 16);
        }

        __syncthreads();

#pragma unroll
        for (int kk = 0; kk < 2; ++kk) {
            bf16x8 af[4], bg[2], bu[2];
#pragma unroll
            for (int mi = 0; mi < 4; ++mi) {
                int row  = wm + mi * 16 + (lane & 15);
                int colb = kk * 64 + ((lane >> 4) * 16);
                af[mi] = *(const bf16x8*)((const char*)At + row * 128 +
                                          (colb ^ ((row & 7) << 4)));
            }
#pragma unroll
            for (int ni = 0; ni < 2; ++ni) {
                int row  = wn + ni * 16 + (lane & 15);
                int colb = kk * 64 + ((lane >> 4) * 16);
                int off  = row * 128 + (colb ^ ((row & 7) << 4));
                bg[ni] = *(const bf16x8*)((const char*)Bg + off);
                bu[ni] = *(const bf16x8*)((const char*)Bu + off);
            }
            __builtin_amdgcn_s_setprio(1);
#pragma unroll
            for (int mi = 0; mi < 4; ++mi)
#pragma unroll
                for (int ni = 0; ni < 2; ++ni) {
                    accG[mi][ni] = __builtin_amdgcn_mfma_f32_16x16x32_bf16(
                        af[mi], bg[ni], accG[mi][ni], 0, 0, 0);
                    accU[mi][ni] = __builtin_amdgcn_mfma_f32_16x16x32_bf16(
                        af[mi], bu[ni], accU[mi][ni], 0, 0, 0);
                }
            __builtin_amdgcn_s_setprio(0);
        }

        __syncthreads();
    }

#pragma unroll
    for (int ni = 0; ni < 2; ++ni) {
        int col = n0 + wn + ni * 16 + (lane & 15);
        float gb = gbias[col], ub = ubias[col];
#pragma unroll
        for (int mi = 0; mi < 4; ++mi) {
#pragma unroll
            for (int j = 0; j < 4; ++j) {
                int row = m0 + wm + mi * 16 + ((lane >> 4) * 4) + j;
                float g = accG[mi][ni][j] + gb;
                float u = accU[mi][ni][j] + ub;
                float sig = 1.f / (1.f + __expf(-g));
                h[(size_t)row * INTER + col] = f2bf(g * sig * u);
            }
        }
    }
}

// ---------------------------------------------------------------------------
// Down GEMM: y = h @ Wd^T + bias (fp32 out). [R4/R9-proven + XCD swizzle]
// 512 thr, tile 128x128, BK=64. Grid 512 = 8 * 64.
// ---------------------------------------------------------------------------
__global__ __launch_bounds__(512) void k_down(
    const unsigned short* __restrict__ h,    // [SEQ][INTER] bf16
    const unsigned short* __restrict__ wd,   // [HIDDEN][INTER] bf16
    const float* __restrict__ dbias,
    float* __restrict__ y)                   // [SEQ][HIDDEN] fp32
{
    __shared__ __align__(16) unsigned short At[128 * 64]; // 16 KB
    __shared__ __align__(16) unsigned short Bd[128 * 64]; // 16 KB

    const int orig = blockIdx.x;                  // 512 = 8 * 64
    const int swz  = (orig & 7) * 64 + (orig >> 3);
    const int mt   = swz & 15;
    const int nt   = swz >> 4;
    const int m0   = mt * 128;
    const int n0   = nt * 128;

    const int t    = threadIdx.x;
    const int lane = t & 63;
    const int wave = t >> 6;
    const int wm = (wave >> 2) * 64;
    const int wn = (wave & 3) * 32;

    f32x4 acc[4][2];
#pragma unroll
    for (int mi = 0; mi < 4; ++mi)
#pragma unroll
        for (int ni = 0; ni < 2; ++ni)
            acc[mi][ni] = (f32x4){0.f, 0.f, 0.f, 0.f};

    for (int kt = 0; kt < INTER / 64; ++kt) {
        const int k0 = kt * 64;

#pragma unroll
        for (int cc = 0; cc < 2; ++cc) {
            int idx  = t + 512 * cc;
            int row  = idx >> 3;
            int scol = ((idx & 7) * 16) ^ ((row & 7) << 4);
            gload_lds16((const char*)(h + (size_t)(m0 + row) * INTER + k0) + scol,
                        (char*)At + idx * 16);
            gload_lds16((const char*)(wd + (size_t)(n0 + row) * INTER + k0) + scol,
                        (char*)Bd + idx * 16);
        }

        __syncthreads();

#pragma unroll
        for (int kk = 0; kk < 2; ++kk) {
            bf16x8 af[4], bd[2];
#pragma unroll
            for (int mi = 0; mi < 4; ++mi) {
                int row  = wm + mi * 16 + (lane & 15);
                int colb = kk * 64 + ((lane >> 4) * 16);
                af[mi] = *(const bf16x8*)((const char*)At + row * 128 +
                                          (colb ^ ((row & 7) << 4)));
            }
#pragma unroll
            for (int ni = 0; ni < 2; ++ni) {
                int row  = wn + ni * 16 + (lane & 15);
                int colb = kk * 64 + ((lane >> 4) * 16);
                bd[ni] = *(const bf16x8*)((const char*)Bd + row * 128 +
                                          (colb ^ ((row & 7) << 4)));
            }
            __builtin_amdgcn_s_setprio(1);
#pragma unroll
            for (int mi = 0; mi < 4; ++mi)
#pragma unroll
                for (int ni = 0; ni < 2; ++ni)
                    acc[mi][ni] = __builtin_amdgcn_mfma_f32_16x16x32_bf16(
                        af[mi], bd[ni], acc[mi][ni], 0, 0, 0);
            __builtin_amdgcn_s_setprio(0);
        }

        __syncthreads();
    }

#pragma unroll
    for (int ni = 0; ni < 2; ++ni) {
        int col = n0 + wn + ni * 16 + (lane & 15);
        float db = dbias[col];
#pragma unroll
        for (int mi = 0; mi < 4; ++mi) {
#pragma unroll
            for (int j = 0; j < 4; ++j) {
                int row = m0 + wm + mi * 16 + ((lane >> 4) * 4) + j;
                y[(size_t)row * HIDDEN + col] = acc[mi][ni][j] + db;
            }
        }
    }
}

// ---------------------------------------------------------------------------
extern "C" void kernel_launch(void* const* d_in, const int* in_sizes, int n_in,
                              void* d_out, int out_size, void* d_ws, size_t ws_size,
                              hipStream_t stream) {
    const float* x    = (const float*)d_in[0];
    const int*   gqw  = (const int*)d_in[1];
    const int*   gqz  = (const int*)d_in[2];
    const float* gsc  = (const float*)d_in[3];
    const float* gbia = (const float*)d_in[4];
    const int*   uqw  = (const int*)d_in[5];
    const int*   uqz  = (const int*)d_in[6];
    const float* usc  = (const float*)d_in[7];
    const float* ubia = (const float*)d_in[8];
    const int*   dqw  = (const int*)d_in[9];
    const int*   dqz  = (const int*)d_in[10];
    const float* dsc  = (const float*)d_in[11];
    const float* dbia = (const float*)d_in[12];
    float* y = (float*)d_out;

    const size_t N_XB = (size_t)SEQ * HIDDEN;      // 8.4M
    const size_t N_H  = (size_t)SEQ * INTER;       // 22.5M
    const size_t N_W  = (size_t)INTER * HIDDEN;    // 45.1M

    unsigned short* xb  = (unsigned short*)d_ws;
    unsigned short* hh  = xb + N_XB;
    unsigned short* wgb = hh + N_H;
    unsigned short* wub = wgb + N_W;

    const size_t need_big = (N_XB + N_H + 3 * N_W) * sizeof(unsigned short);
    const bool   big      = ws_size >= need_big;

    // prep: cvt + dequant gate + dequant up (2048 + 11008 + 11008 blocks)
    k_prep<<<dim3(24064), 512, 0, stream>>>(x, xb, gqw, gqz, gsc, wgb,
                                            uqw, uqz, usc, wub);

    if (big) {
        unsigned short* wdb = wub + N_W;           // de-aliased down weights
        // GEMM (1376) + co-scheduled down-dequant (11008) in one grid
        k_gate_up<<<dim3(1376 + 11008), 512, 0, stream>>>(
            xb, wgb, wub, gbia, ubia, hh, dqw, dqz, dsc, wdb);
        k_down<<<dim3(512), 512, 0, stream>>>(hh, wdb, dbia, y);
    } else {
        unsigned short* wdb = wgb;                 // alias: serial fallback
        k_gate_up<<<dim3(1376), 512, 0, stream>>>(
            xb, wgb, wub, gbia, ubia, hh, dqw, dqz, dsc, wdb);
        k_deq_fb<<<dim3(11008), 512, 0, stream>>>(dqw, dqz, dsc, wdb);
        k_down<<<dim3(512), 512, 0, stream>>>(hh, wdb, dbia, y);
    }
}